// Round 6
// baseline (783.301 us; speedup 1.0000x reference)
//
#include <hip/hip_runtime.h>

#define LOG2E 1.44269504088896340736f

typedef _Float16 f16;
typedef __attribute__((ext_vector_type(4))) _Float16 f16x4;
typedef __attribute__((ext_vector_type(8))) _Float16 f16x8;
typedef __attribute__((ext_vector_type(4))) float f32x4;
typedef __attribute__((ext_vector_type(8))) unsigned short us8;

#define BB 32
#define SSX 2048
#define SSY 2048
#define DD 160
#define M_TOTAL (BB*SSX)   // 65536

#define PRS 168    // proj input LDS row stride (f16)
#define V2RS 72    // proj V^T store buffer stride (64 + 8)
#define RS 168     // flash K/Q LDS stride
#define P_RS 72    // flash P stride (overlaid in K_lds)

__device__ __forceinline__ f32x4 mfma16(f16x8 a, f16x8 b, f32x4 c) {
  return __builtin_amdgcn_mfma_f32_16x16x32_f16(a, b, c, 0, 0, 0);
}

// max over the 16-lane DPP row (= C/D layout column group) via row_ror — pure VALU,
// replaces 4 serial ds_swizzle (LDS pipe, ~30cyc latency each)
__device__ __forceinline__ float rmax16(float x) {
  x = fmaxf(x, __int_as_float(__builtin_amdgcn_update_dpp(0, __float_as_int(x), 0x121, 0xf, 0xf, true)));
  x = fmaxf(x, __int_as_float(__builtin_amdgcn_update_dpp(0, __float_as_int(x), 0x122, 0xf, 0xf, true)));
  x = fmaxf(x, __int_as_float(__builtin_amdgcn_update_dpp(0, __float_as_int(x), 0x124, 0xf, 0xf, true)));
  x = fmaxf(x, __int_as_float(__builtin_amdgcn_update_dpp(0, __float_as_int(x), 0x128, 0xf, 0xf, true)));
  return x;
}

// ---- W fp32 -> f16 pre-convert (once; proj then reads W frags from L2-resident f16) ----
__global__ __launch_bounds__(256) void wconv_kernel(
    const float* __restrict__ Wq, const float* __restrict__ Wk, const float* __restrict__ Wv,
    f16* __restrict__ Wf)
{
  const int bid = blockIdx.x;
  const int kind = bid / 25;
  const int j = (bid % 25)*1024 + threadIdx.x*4;
  const float* W = (kind == 0) ? Wq : (kind == 1 ? Wk : Wv);
  float4 v = *(const float4*)&W[j];
  f16x4 h = { (f16)v.x, (f16)v.y, (f16)v.z, (f16)v.w };
  *(f16x4*)&Wf[kind*25600 + j] = h;
}

// ---- Projection: 64-row tiles, one projection per block (kind 0=Q,1=K,2=V).
// No W LDS staging: B-frags read directly from f16 W (L2-resident). LDS=23KB -> 4 blocks/CU.
__global__ __launch_bounds__(256, 4) void proj_kernel(
    const float* __restrict__ x, const float* __restrict__ y,
    const f16* __restrict__ Wf16,
    const float* __restrict__ bq, const float* __restrict__ bk, const float* __restrict__ bv,
    f16* __restrict__ Qw, f16* __restrict__ Kw, f16* __restrict__ Vtw)
{
  __shared__ __align__(16) f16 buf[160*V2RS];  // 23040 B (>= 64*PRS = 10752 f16? no: holds max(64*168,160*72)=11520 f16)
  const int t = threadIdx.x;
  const int wave = t >> 6;
  const int lane = t & 63;
  const int quad = lane >> 4;
  const int l16  = lane & 15;
  const int bid  = blockIdx.x;
  const int kind = bid % 3;          // K,V adjacent -> L2 reuse of y tile
  const int tile = bid / 3;
  const int row0 = tile * 64;
  const float* src  = (kind == 0) ? x  : y;
  const f16*   Wf   = Wf16 + kind*25600;
  const float* bias = (kind == 0) ? bq : (kind == 1 ? bk : bv);

  // stage 64x160 input tile fp32 -> f16
  for (int i = 0; i < 10; ++i) {
    int idx = t + i*256;             // 2560 float4
    int r = idx / 40, c4 = idx % 40;
    float4 v = *(const float4*)&src[(size_t)(row0 + r)*DD + c4*4];
    f16x4 h = { (f16)v.x, (f16)v.y, (f16)v.z, (f16)v.w };
    *(f16x4*)&buf[r*PRS + c4*4] = h;
  }
  __syncthreads();
  f16x8 afr[5];
  #pragma unroll
  for (int ks = 0; ks < 5; ++ks)
    afr[ks] = *(const f16x8*)&buf[(wave*16 + l16)*PRS + ks*32 + quad*8];

  f32x4 acc[10];
  #pragma unroll
  for (int nt = 0; nt < 10; ++nt) {
    float bs = bias[nt*16 + l16];
    acc[nt] = (f32x4){bs,bs,bs,bs};
    #pragma unroll
    for (int ks = 0; ks < 5; ++ks) {
      f16x8 bfr = *(const f16x8*)&Wf[(nt*16 + l16)*160 + ks*32 + quad*8];
      acc[nt] = mfma16(afr[ks], bfr, acc[nt]);
    }
  }
  __syncthreads();   // input-tile reads done before buf reuse

  if (kind < 2) {
    f16* dst = (kind == 0) ? Qw : Kw;
    #pragma unroll
    for (int nt = 0; nt < 10; ++nt)
      #pragma unroll
      for (int r = 0; r < 4; ++r)
        buf[(wave*16 + quad*4 + r)*PRS + nt*16 + l16] = (f16)acc[nt][r];
    __syncthreads();
    for (int i = 0; i < 5; ++i) {
      int idx = t + i*256;           // 1280 us8 = 64x160 f16
      int r = idx / 20, g = idx % 20;
      *(us8*)&dst[(size_t)(row0 + r)*DD + g*8] = *(const us8*)&buf[r*PRS + g*8];
    }
  } else {
    // V^T: acc -> buf[d][y_local] (stride V2RS) -> coalesced us8 stores
    #pragma unroll
    for (int nt = 0; nt < 10; ++nt)
      #pragma unroll
      for (int r = 0; r < 4; ++r)
        buf[(nt*16 + l16)*V2RS + wave*16 + quad*4 + r] = (f16)acc[nt][r];
    __syncthreads();
    const int b  = row0 / SSY;
    const int y0 = row0 % SSY;
    for (int i = 0; i < 5; ++i) {
      int idx = t + i*256;           // 1280 us8 = 160 d x 64 y
      int d = idx / 8, yg = idx % 8;
      *(us8*)&Vtw[((size_t)b*DD + d)*SSY + y0 + yg*8] = *(const us8*)&buf[d*V2RS + yg*8];
    }
  }
}

// ---------------- Flash attention + residual: 128 q-rows/block, 32 q-rows/wave ----------------
// P overlaid on K_lds (3rd barrier guards the overwrite) -> 44032 B LDS -> 3 blocks/CU.

#define LOAD_CHUNK(yb) { \
  const f16* ksrc = Kw + ((size_t)b*SSY + (yb))*DD; \
  const f16* vsrc = Vtw + (size_t)b*DD*SSY + (yb); \
  _Pragma("unroll") \
  for (int i = 0; i < 5; ++i) { \
    int idx = t + i*256; int r = idx/20, c = idx%20; \
    kreg[i] = *(const us8*)&ksrc[(size_t)r*DD + c*8]; \
  } \
  _Pragma("unroll") \
  for (int i = 0; i < 5; ++i) { \
    int idx = t + i*256; int d = idx>>3, g = idx&7; \
    vreg[i] = *(const us8*)&vsrc[(size_t)d*SSY + g*8]; \
  } \
}

#define STORE_CHUNK() { \
  _Pragma("unroll") \
  for (int i = 0; i < 5; ++i) { \
    int idx = t + i*256; int r = idx/20, c = idx%20; \
    *(us8*)&K_lds[r*RS + c*8] = kreg[i]; \
  } \
  _Pragma("unroll") \
  for (int i = 0; i < 5; ++i) { \
    int idx = t + i*256; int d = idx>>3, g = idx&7; \
    *(us8*)&Vt_lds[d*64 + ((g ^ (d & 7)) << 3)] = vreg[i]; \
  } \
}

__global__ __launch_bounds__(256, 3) void flash_kernel(
    const f16* __restrict__ Qw, const f16* __restrict__ Kw, const f16* __restrict__ Vtw,
    const float* __restrict__ x, float* __restrict__ out)
{
  __shared__ __align__(16) f16 K_lds[64*RS];      // 21504 B (Q staging, K frags, then P overlay)
  __shared__ __align__(16) f16 Vt_lds[176*64];    // 22528 B (rows 160..175: ones-column tile)
  const int t = threadIdx.x;
  const int wave = t >> 6;
  const int lane = t & 63;
  const int quad = lane >> 4;
  const int l16  = lane & 15;
  const int bid  = blockIdx.x;
  const int b    = bid >> 4;
  const int x0   = (bid & 15) * 128;

  // ones-tile init: row 160 = 1.0 (l-accumulator column), rows 161..175 = 0
  for (int idx = t; idx < 1024; idx += 256) {
    int d = idx >> 6, yy = idx & 63;
    Vt_lds[(160 + d)*64 + yy] = (d == 0) ? (f16)1.0f : (f16)0.0f;
  }

  // stage Q (128 rows in two 64-row passes through K_lds), hoist A-frags (32 rows/wave)
  f16x8 qfr0[5], qfr1[5];
  #pragma unroll
  for (int h = 0; h < 2; ++h) {
    if (h) __syncthreads();
    const f16* qsrc = Qw + ((size_t)b*SSX + x0 + h*64)*DD;
    for (int i = 0; i < 5; ++i) {
      int idx = t + i*256;
      int r = idx / 20, c = idx % 20;
      *(us8*)&K_lds[r*RS + c*8] = *(const us8*)&qsrc[(size_t)r*DD + c*8];
    }
    __syncthreads();
    if ((wave >> 1) == h) {
      const int base = (wave & 1)*32;
      #pragma unroll
      for (int ks = 0; ks < 5; ++ks) {
        qfr0[ks] = *(const f16x8*)&K_lds[(base + l16)*RS + ks*32 + quad*8];
        qfr1[ks] = *(const f16x8*)&K_lds[(base + 16 + l16)*RS + ks*32 + quad*8];
      }
    }
  }

  f32x4 acc0[11], acc1[11];   // tile 10 = l (ones column)
  #pragma unroll
  for (int i = 0; i < 11; ++i) { acc0[i] = (f32x4){0.f,0.f,0.f,0.f}; acc1[i] = (f32x4){0.f,0.f,0.f,0.f}; }
  float m0[4], m1[4];
  #pragma unroll
  for (int r = 0; r < 4; ++r) { m0[r] = -1e30f; m1[r] = -1e30f; }

  f16* Pw = &K_lds[wave*32*P_RS];   // P overlay: 4*32*72*2 = 18432 <= 21504
  us8 kreg[5], vreg[5];

  LOAD_CHUNK(0);
  for (int yc = 0; yc < SSY/64; ++yc) {
    __syncthreads();          // A: all waves done with prev PV reads (P region + Vt)
    STORE_CHUNK();
    __syncthreads();          // B: K/V staged
    if (yc < SSY/64 - 1) LOAD_CHUNK((yc+1)*64);   // prefetch overlaps compute

    // S = Q K^T  (two 16-row groups share each K fragment)
    f32x4 S0[4], S1[4];
    #pragma unroll
    for (int nt = 0; nt < 4; ++nt) { S0[nt] = (f32x4){0.f,0.f,0.f,0.f}; S1[nt] = (f32x4){0.f,0.f,0.f,0.f}; }
    #pragma unroll
    for (int nt = 0; nt < 4; ++nt)
      #pragma unroll
      for (int ks = 0; ks < 5; ++ks) {
        f16x8 kfr = *(const f16x8*)&K_lds[(nt*16 + l16)*RS + ks*32 + quad*8];
        S0[nt] = mfma16(qfr0[ks], kfr, S0[nt]);
        S1[nt] = mfma16(qfr1[ks], kfr, S1[nt]);
      }
    __syncthreads();          // C: all waves done reading K before P overlay write

    // online softmax (l via ones-column MFMA; max-reduce via DPP, pure VALU)
    float n0[4], n1[4];
    bool changed = false;
    #pragma unroll
    for (int r = 0; r < 4; ++r) {
      float a = fmaxf(fmaxf(S0[0][r], S0[1][r]), fmaxf(S0[2][r], S0[3][r]));
      n0[r] = fmaxf(m0[r], rmax16(a));
      changed = changed || (n0[r] > m0[r]);
      float c = fmaxf(fmaxf(S1[0][r], S1[1][r]), fmaxf(S1[2][r], S1[3][r]));
      n1[r] = fmaxf(m1[r], rmax16(c));
      changed = changed || (n1[r] > m1[r]);
    }
    if (__any(changed)) {
      f32x4 av0, av1;
      #pragma unroll
      for (int r = 0; r < 4; ++r) {
        av0[r] = exp2f((m0[r] - n0[r])*LOG2E); m0[r] = n0[r];
        av1[r] = exp2f((m1[r] - n1[r])*LOG2E); m1[r] = n1[r];
      }
      #pragma unroll
      for (int i = 0; i < 11; ++i) { acc0[i] *= av0; acc1[i] *= av1; }
    }

    // P = exp(S - m) -> LDS (C/D layout -> A-operand layout round trip)
    #pragma unroll
    for (int r = 0; r < 4; ++r)
      #pragma unroll
      for (int nt = 0; nt < 4; ++nt) {
        Pw[(quad*4 + r)*P_RS + nt*16 + l16]      = (f16)exp2f((S0[nt][r] - m0[r])*LOG2E);
        Pw[(16 + quad*4 + r)*P_RS + nt*16 + l16] = (f16)exp2f((S1[nt][r] - m1[r])*LOG2E);
      }

    // acc += P V (tile 10 accumulates l via ones column); V fragments shared by both groups
    #pragma unroll
    for (int k2 = 0; k2 < 2; ++k2) {
      f16x8 p0 = *(const f16x8*)&Pw[l16*P_RS + k2*32 + quad*8];
      f16x8 p1 = *(const f16x8*)&Pw[(16 + l16)*P_RS + k2*32 + quad*8];
      #pragma unroll
      for (int dt = 0; dt < 11; ++dt) {
        f16x8 vfr = *(const f16x8*)&Vt_lds[(dt*16 + l16)*64 + (((k2*4 + quad) ^ (l16 & 7)) << 3)];
        acc0[dt] = mfma16(p0, vfr, acc0[dt]);
        acc1[dt] = mfma16(p1, vfr, acc1[dt]);
      }
    }
  }

  // epilogue: l = acc[10] col 0 (lanes quad*16), broadcast; out = acc/l + x
  float rl0[4], rl1[4];
  #pragma unroll
  for (int r = 0; r < 4; ++r) {
    rl0[r] = 1.f / __shfl(acc0[10][r], lane & 48);
    rl1[r] = 1.f / __shfl(acc1[10][r], lane & 48);
  }
  const size_t base = ((size_t)b*SSX + x0 + wave*32)*DD;
  #pragma unroll
  for (int dt = 0; dt < 10; ++dt)
    #pragma unroll
    for (int r = 0; r < 4; ++r) {
      size_t o0 = base + (size_t)(quad*4 + r)*DD + dt*16 + l16;
      size_t o1 = base + (size_t)(16 + quad*4 + r)*DD + dt*16 + l16;
      out[o0] = acc0[dt][r]*rl0[r] + x[o0];
      out[o1] = acc1[dt][r]*rl1[r] + x[o1];
    }
}

extern "C" void kernel_launch(void* const* d_in, const int* in_sizes, int n_in,
                              void* d_out, int out_size, void* d_ws, size_t ws_size,
                              hipStream_t stream) {
  const float* x  = (const float*)d_in[0];
  const float* y  = (const float*)d_in[1];
  const float* Wq = (const float*)d_in[2];
  const float* bq = (const float*)d_in[3];
  const float* Wk = (const float*)d_in[4];
  const float* bk = (const float*)d_in[5];
  const float* Wv = (const float*)d_in[6];
  const float* bv = (const float*)d_in[7];

  f16* Qw  = (f16*)d_ws;
  f16* Kw  = Qw + (size_t)M_TOTAL*DD;
  f16* Vtw = Kw + (size_t)M_TOTAL*DD;
  f16* Wf  = Vtw + (size_t)M_TOTAL*DD;   // 3*25600 f16 = 150 KB extra (total ~63.1 MB)

  wconv_kernel<<<75, 256, 0, stream>>>(Wq, Wk, Wv, Wf);
  proj_kernel<<<3072, 256, 0, stream>>>(x, y, Wf, bq, bk, bv, Qw, Kw, Vtw);
  flash_kernel<<<512, 256, 0, stream>>>(Qw, Kw, Vtw, x, (float*)d_out);
}